// Round 7
// baseline (29.270 us; speedup 1.0000x reference)
//
#include <hip/hip_runtime.h>

#define N_SAMPLES 32768
#define N_EVENTS 16
#define HOP 256
#define TILE 1024   // samples per tile = 256 threads * 4 floats

typedef float f32x4 __attribute__((ext_vector_type(4)));

__global__ __launch_bounds__(256) void ola_gather_kernel(
    const float* __restrict__ x,     // (128, 16, 32768)
    const int* __restrict__ indices, // (128, 16)
    float* __restrict__ out)         // (128, 32768)
{
    const int b = blockIdx.x & 127;  // batch
    const int p = blockIdx.x >> 7;   // 0..3 -> tile octet

    const float* xb = x + (size_t)b * N_EVENTS * N_SAMPLES;
    float*       ob = out + (size_t)b * N_SAMPLES;
    const int*   ib = indices + b * N_EVENTS;

    // Wave-uniform starts (scalar loads), multiples of 256.
    int start[N_EVENTS];
#pragma unroll
    for (int i = 0; i < N_EVENTS; ++i) start[i] = ib[i] * HOP;

    // Eight tiles per block with constant total work:
    // p + (7-p) + (8+p) + (15-p) + (16+p) + (23-p) + (24+p) + (31-p) = 124.
    const int tiles[8] = {p, 7 - p, 8 + p, 15 - p, 16 + p, 23 - p, 24 + p, 31 - p};

#pragma unroll
    for (int t = 0; t < 8; ++t) {
        const int s0 = tiles[t] * TILE + threadIdx.x * 4;

        // Issue ALL 16 loads unconditionally (clamped offsets stay in-row),
        // then mask on accumulate: 16 independent dwordx4 in flight.
        f32x4 vals[N_EVENTS];
        int   offs[N_EVENTS];
#pragma unroll
        for (int i = 0; i < N_EVENTS; ++i) {
            const int off = s0 - start[i];
            offs[i] = off;
            const int offc = off > 0 ? off : 0;
            vals[i] = *reinterpret_cast<const f32x4*>(
                xb + (size_t)i * N_SAMPLES + offc);
        }

        f32x4 acc = (f32x4)0.f;
#pragma unroll
        for (int i = 0; i < N_EVENTS; ++i) {
            acc += (offs[i] >= 0) ? vals[i] : (f32x4)0.f;
        }

        __builtin_nontemporal_store(acc, reinterpret_cast<f32x4*>(ob + s0));
    }
}

extern "C" void kernel_launch(void* const* d_in, const int* in_sizes, int n_in,
                              void* d_out, int out_size, void* d_ws, size_t ws_size,
                              hipStream_t stream) {
    const float* x       = (const float*)d_in[0];
    const int*   indices = (const int*)d_in[1];
    float*       out     = (float*)d_out;

    // 128 batches * 4 tile-octets = 512 blocks
    ola_gather_kernel<<<512, 256, 0, stream>>>(x, indices, out);
}

// Round 8
// 28.709 us; speedup vs baseline: 1.0195x; 1.0195x over previous
//
#include <hip/hip_runtime.h>

#define N_SAMPLES 32768
#define N_EVENTS 16
#define HOP 256
#define TILE 1024   // samples per tile = 256 threads * 4 floats

typedef float f32x4 __attribute__((ext_vector_type(4)));

// Best measured configuration (R6): 1024 blocks, 4 work-balanced tiles per
// block, branchless 16-deep-ILP gather body. Block-count curve mapped:
// 4096->29.7us, 2048->28.76, 1024->28.43 (min), 512->29.27.
__global__ __launch_bounds__(256) void ola_gather_kernel(
    const float* __restrict__ x,     // (128, 16, 32768)
    const int* __restrict__ indices, // (128, 16)
    float* __restrict__ out)         // (128, 32768)
{
    const int b = blockIdx.x & 127;  // batch
    const int p = blockIdx.x >> 7;   // 0..7 -> tile quad {p, 15-p, 16+p, 31-p}

    const float* xb = x + (size_t)b * N_EVENTS * N_SAMPLES;
    float*       ob = out + (size_t)b * N_SAMPLES;
    const int*   ib = indices + b * N_EVENTS;

    // Wave-uniform starts (scalar loads), multiples of 256.
    int start[N_EVENTS];
#pragma unroll
    for (int i = 0; i < N_EVENTS; ++i) start[i] = ib[i] * HOP;

    // Four tiles per block with constant total work:
    // p + (15-p) + (16+p) + (31-p) = 62 for every p.
    const int tiles[4] = {p, 15 - p, 16 + p, 31 - p};

#pragma unroll
    for (int t = 0; t < 4; ++t) {
        const int s0 = tiles[t] * TILE + threadIdx.x * 4;

        // Issue ALL 16 loads unconditionally (clamped offsets stay in-row),
        // then mask on accumulate: 16 independent dwordx4 in flight.
        f32x4 vals[N_EVENTS];
        int   offs[N_EVENTS];
#pragma unroll
        for (int i = 0; i < N_EVENTS; ++i) {
            const int off = s0 - start[i];
            offs[i] = off;
            const int offc = off > 0 ? off : 0;
            vals[i] = *reinterpret_cast<const f32x4*>(
                xb + (size_t)i * N_SAMPLES + offc);
        }

        f32x4 acc = (f32x4)0.f;
#pragma unroll
        for (int i = 0; i < N_EVENTS; ++i) {
            acc += (offs[i] >= 0) ? vals[i] : (f32x4)0.f;
        }

        __builtin_nontemporal_store(acc, reinterpret_cast<f32x4*>(ob + s0));
    }
}

extern "C" void kernel_launch(void* const* d_in, const int* in_sizes, int n_in,
                              void* d_out, int out_size, void* d_ws, size_t ws_size,
                              hipStream_t stream) {
    const float* x       = (const float*)d_in[0];
    const int*   indices = (const int*)d_in[1];
    float*       out     = (float*)d_out;

    // 128 batches * 8 tile-quads = 1024 blocks
    ola_gather_kernel<<<1024, 256, 0, stream>>>(x, indices, out);
}